// Round 3
// baseline (189.191 us; speedup 1.0000x reference)
//
#include <hip/hip_runtime.h>
#include <hip/hip_bf16.h>

typedef unsigned short u16;
typedef unsigned int u32;
typedef __attribute__((ext_vector_type(8))) short bf16x8;
typedef __attribute__((ext_vector_type(4))) float f32x4;

#define NB 4096
#define ND 512
#define NREPS (3*NB)
#define BM 256
#define BN 256
#define BK 64
#define NKT (ND/BK)        // 8 K-tiles
#define TSZ (BM*BK)        // elements per (A or B) tile buffer

// global -> LDS direct DMA, 16B/lane; LDS dest wave-uniform base + lane*16.
#define GLD16(gp, lp)                                                         \
  __builtin_amdgcn_global_load_lds(                                           \
      (const __attribute__((address_space(1))) void*)(gp),                    \
      (__attribute__((address_space(3))) void*)(lp), 16, 0, 0)
// Counted wait: never drain the prefetch queue (T4). Derived: min prefetch
// distance = 6 phases = 3 stages in flight after wait = 6 loads... uniform 10
// because 5 stages x 2 loads remain outstanding at every phase boundary.
#define VMW asm volatile("s_waitcnt vmcnt(10)" ::: "memory")
#define BAR __builtin_amdgcn_s_barrier()

__device__ __forceinline__ u16 f2bf(float f) {
  union { float f; u32 u; } v; v.f = f;
  u32 u = v.u;
  u32 r = (u + 0x7FFFu + ((u >> 16) & 1u)) >> 16;  // round-to-nearest-even
  return (u16)r;
}

// Fused prep: waves 0..2 convert ts/i1/i2 row r -> bf16 reps + fp32 norms;
// i1/i2 rows pass through LDS to wave 3 (dist12 + minsq init).
__global__ __launch_bounds__(256) void prep_all(
    const float* __restrict__ ts, const float* __restrict__ i1,
    const float* __restrict__ i2, u16* __restrict__ reps,
    float* __restrict__ norms, float* __restrict__ dist12,
    u32* __restrict__ minsq)
{
  __shared__ float s1[ND], s2[ND];
  const int r = blockIdx.x;
  const int tid = threadIdx.x;
  const int wave = tid >> 6, lane = tid & 63;

  if (wave < 3) {
    const float* src = (wave == 0) ? ts + (size_t)r * ND
                     : (wave == 1) ? i1 + (size_t)r * ND
                     :               i2 + (size_t)r * ND;
    const float4* s4 = (const float4*)src;
    float4 a = s4[lane*2+0];
    float4 b = s4[lane*2+1];
    if (wave == 1) { ((float4*)s1)[lane*2+0] = a; ((float4*)s1)[lane*2+1] = b; }
    if (wave == 2) { ((float4*)s2)[lane*2+0] = a; ((float4*)s2)[lane*2+1] = b; }
    float ss = a.x*a.x + a.y*a.y + a.z*a.z + a.w*a.w
             + b.x*b.x + b.y*b.y + b.z*b.z + b.w*b.w;
    uint4 pk;
    pk.x = (u32)f2bf(a.x) | ((u32)f2bf(a.y) << 16);
    pk.y = (u32)f2bf(a.z) | ((u32)f2bf(a.w) << 16);
    pk.z = (u32)f2bf(b.x) | ((u32)f2bf(b.y) << 16);
    pk.w = (u32)f2bf(b.z) | ((u32)f2bf(b.w) << 16);
    *(uint4*)(reps + (size_t)(wave*NB + r) * ND + lane*8) = pk;
    #pragma unroll
    for (int off = 32; off; off >>= 1) ss += __shfl_down(ss, off);
    if (lane == 0) norms[wave*NB + r] = ss;
  }
  __syncthreads();
  if (wave == 3) {
    float ss = 0.f;
    #pragma unroll
    for (int i = 0; i < 2; ++i) {
      float4 a = ((float4*)s1)[lane*2+i];
      float4 b = ((float4*)s2)[lane*2+i];
      float d0 = a.x - b.x + 1e-6f, d1 = a.y - b.y + 1e-6f;
      float d2 = a.z - b.z + 1e-6f, d3 = a.w - b.w + 1e-6f;
      ss += d0*d0 + d1*d1 + d2*d2 + d3*d3;
    }
    #pragma unroll
    for (int off = 32; off; off >>= 1) ss += __shfl_down(ss, off);
    if (lane == 0) { dist12[r] = sqrtf(ss); minsq[r] = 0x7F800000u; }
  }
}

__device__ __forceinline__ void rdA(const u16* __restrict__ S, int wr, int fr,
                                    int fg, int mfB, bf16x8 a[4][2]) {
  #pragma unroll
  for (int mf = 0; mf < 4; ++mf)
    #pragma unroll
    for (int ks = 0; ks < 2; ++ks) {
      const int ra = wr*128 + (mfB+mf)*16 + fr;
      a[mf][ks] = *(const bf16x8*)&S[ra*BK + ((ks*4+fg) ^ (ra & 7))*8];
    }
}
__device__ __forceinline__ void rdB(const u16* __restrict__ S, int wc, int fr,
                                    int fg, int nfB, bf16x8 b[2][2]) {
  #pragma unroll
  for (int nf = 0; nf < 2; ++nf)
    #pragma unroll
    for (int ks = 0; ks < 2; ++ks) {
      const int rb = wc*64 + (nfB+nf)*16 + fr;
      b[nf][ks] = *(const bf16x8*)&S[rb*BK + ((ks*4+fg) ^ (rb & 7))*8];
    }
}
__device__ __forceinline__ void q_mfma(const bf16x8 a[4][2], const bf16x8 b[2][2],
                                       f32x4 acc[8][4], int mfB, int nfB) {
  #pragma unroll
  for (int ks = 0; ks < 2; ++ks)
    #pragma unroll
    for (int mf = 0; mf < 4; ++mf)
      #pragma unroll
      for (int nf = 0; nf < 2; ++nf)
        acc[mfB+mf][nfB+nf] = __builtin_amdgcn_mfma_f32_16x16x32_bf16(
            a[mf][ks], b[nf][ks], acc[mfB+mf][nfB+nf], 0, 0, 0);
}

// 256x256 tile, BK=64, 8 waves (2Mx4N), 4-phase/K-tile counted-vmcnt pipeline.
// LDS: 2 x (A 32KB + B 32KB) = 128KB. Regions: A-lo = m-frag 0-3 rows
// ([0,64)u[128,192)), A-hi = +64; B-lo = per-stripe rows wc*64+[0,32), B-hi=+32.
// Stage schedule: p0 Bhi(t+1)->nxt, p1 Alo(t+2)->cur, p2 Blo(t+2)->cur,
// p3 Ahi(t+2)->cur. Each region overwritten >=1 barrier after its last read.
__global__ __launch_bounds__(512) void gemm_min(
    const u16* __restrict__ reps, const float* __restrict__ norms,
    u32* __restrict__ minsq, float* __restrict__ lpos1,
    float* __restrict__ lpos2)
{
  __shared__ u16 As[2*TSZ];
  __shared__ u16 Bs[2*TSZ];
  const int tid  = threadIdx.x;
  const int lane = tid & 63;
  const int wave = tid >> 6;          // 0..7
  const int wr = wave >> 2;           // 0..1 (M half)
  const int wc = wave & 3;            // 0..3 (N quarter)
  const int fr = lane & 15, fg = lane >> 4;

  // XCD-aware bijective swizzle (768 % 8 == 0), column-major work order.
  const int wid = (blockIdx.x & 7) * 96 + (blockIdx.x >> 3);
  const int mx = wid & 15, ny = wid >> 4;
  const int rowBase = mx * BM;        // ts rows
  const int colBase = ny * BN;        // reps rows

  // Staging geometry: chunk c = wave*2+i covers 8 rows (1 GLD = 1KB).
  const int c0 = wave * 2;
  const int rA0 = (c0 < 8) ? c0*8 : 128 + (c0-8)*8;       // A-lo row base
  const int rB0 = (c0 >> 2)*64 + (c0 & 3)*8;              // B-lo row base
  const int gsw = (lane & 7) ^ (lane >> 3);               // src granule swizzle
  const u16* gA = reps + (size_t)(rowBase + rA0 + (lane>>3))*ND + gsw*8;
  const u16* gB = reps + (size_t)(colBase + rB0 + (lane>>3))*ND + gsw*8;
  u16* lA = As + rA0*BK;
  u16* lB = Bs + rB0*BK;

#define ST_ALO(b,k) { GLD16(gA + (k),         lA + (b)*TSZ);          \
                      GLD16(gA + 8*ND + (k),  lA + (b)*TSZ + 8*BK); }
#define ST_AHI(b,k) { GLD16(gA + 64*ND + (k), lA + (b)*TSZ + 64*BK);  \
                      GLD16(gA + 72*ND + (k), lA + (b)*TSZ + 72*BK); }
#define ST_BLO(b,k) { GLD16(gB + (k),         lB + (b)*TSZ);          \
                      GLD16(gB + 8*ND + (k),  lB + (b)*TSZ + 8*BK); }
#define ST_BHI(b,k) { GLD16(gB + 32*ND + (k), lB + (b)*TSZ + 32*BK);  \
                      GLD16(gB + 40*ND + (k), lB + (b)*TSZ + 40*BK); }

  f32x4 acc[8][4];
  const f32x4 zero = {0.f, 0.f, 0.f, 0.f};
  #pragma unroll
  for (int i = 0; i < 8; ++i)
    #pragma unroll
    for (int j = 0; j < 4; ++j) acc[i][j] = zero;

  bf16x8 aLo[4][2], aHi[4][2], bb[2][2];

  // Prologue: 7 stages (14 loads/thread) = tiles 0 full + tile 1 minus Bhi.
  ST_ALO(0, 0); ST_BLO(0, 0); ST_AHI(0, 0); ST_BHI(0, 0);
  ST_ALO(1, BK); ST_BLO(1, BK); ST_AHI(1, BK);

  for (int t = 0; t < NKT; ++t) {
    const int cur = t & 1, nxt = cur ^ 1;
    const u16* Sa = As + cur*TSZ;
    const u16* Sb = Bs + cur*TSZ;
    const int k1 = (t+1)*BK, k2 = (t+2)*BK;  // tail stages read harmless
                                             // in-workspace garbage, never used
    // p0: needs Alo(t),Blo(t) landed -> vmcnt(10) exact
    VMW; ST_BHI(nxt, k1);
    rdA(Sa, wr, fr, fg, 0, aLo); rdB(Sb, wc, fr, fg, 0, bb);
    __builtin_amdgcn_s_setprio(1); q_mfma(aLo, bb, acc, 0, 0);
    __builtin_amdgcn_s_setprio(0); BAR;
    // p1: needs Ahi(t)
    VMW; ST_ALO(cur, k2);
    rdA(Sa, wr, fr, fg, 4, aHi);
    __builtin_amdgcn_s_setprio(1); q_mfma(aHi, bb, acc, 4, 0);
    __builtin_amdgcn_s_setprio(0); BAR;
    // p2: needs Bhi(t)
    VMW; ST_BLO(cur, k2);
    rdB(Sb, wc, fr, fg, 2, bb);
    __builtin_amdgcn_s_setprio(1); q_mfma(aLo, bb, acc, 0, 2);
    __builtin_amdgcn_s_setprio(0); BAR;
    // p3: no new LDS reads (regs held)
    VMW; ST_AHI(cur, k2);
    __builtin_amdgcn_s_setprio(1); q_mfma(aHi, bb, acc, 4, 2);
    __builtin_amdgcn_s_setprio(0); BAR;
  }

  // Epilogue: sq = nt + nc - 2*dot; diagonal picks; row-min with exclusions.
  // C layout: col = fr, row = fg*4 + q within each 16x16 fragment.
  float ncol[4];
  #pragma unroll
  for (int nf = 0; nf < 4; ++nf)
    ncol[nf] = norms[colBase + wc*64 + nf*16 + fr];
  const float INF = __builtin_inff();
  #pragma unroll
  for (int mf = 0; mf < 8; ++mf) {
    #pragma unroll
    for (int q = 0; q < 4; ++q) {
      const int r_g = rowBase + wr*128 + mf*16 + fg*4 + q;
      const float ntr = norms[r_g];
      float vm = INF;
      #pragma unroll
      for (int nf = 0; nf < 4; ++nf) {
        const int c_g = colBase + wc*64 + nf*16 + fr;
        const float dot = acc[mf][nf][q];
        const float sq = ntr + ncol[nf] - 2.0f * dot;
        if (c_g == r_g + NB)   lpos1[r_g] = sq;   // unique writer
        if (c_g == r_g + 2*NB) lpos2[r_g] = sq;   // unique writer
        const bool excl = (c_g == r_g) || (c_g == r_g + NB) || (c_g == r_g + 2*NB);
        const float v = excl ? INF : fmaxf(sq, 0.0f);
        vm = fminf(vm, v);
      }
      #pragma unroll
      for (int off = 1; off < 16; off <<= 1)
        vm = fminf(vm, __shfl_xor(vm, off));
      if (fr == 0)
        atomicMin(minsq + r_g, __float_as_uint(vm));  // nonneg floats order as uints
    }
  }
}

__global__ __launch_bounds__(1024) void finalize(
    const float* __restrict__ lpos1, const float* __restrict__ lpos2,
    const float* __restrict__ dist12, const u32* __restrict__ minsq,
    float* __restrict__ out)
{
  __shared__ float red[16];
  const int tid = threadIdx.x;
  float s = 0.f;
  for (int r = tid; r < NB; r += 1024) {
    float l1 = sqrtf(fmaxf(lpos1[r], 0.f));
    float l2 = sqrtf(fmaxf(lpos2[r], 0.f));
    float neg = sqrtf(__uint_as_float(minsq[r]));   // already clamped >= 0
    float pos = l1 + l2 + dist12[r];
    s += fmaxf(pos - neg + 0.1f, 0.f) + fmaxf(l1, l2);
  }
  #pragma unroll
  for (int off = 32; off; off >>= 1) s += __shfl_down(s, off);
  if ((tid & 63) == 0) red[tid >> 6] = s;
  __syncthreads();
  if (tid == 0) {
    float t = 0.f;
    #pragma unroll
    for (int i = 0; i < 16; ++i) t += red[i];
    out[0] = t * (1.0f / NB);
  }
}

extern "C" void kernel_launch(void* const* d_in, const int* in_sizes, int n_in,
                              void* d_out, int out_size, void* d_ws, size_t ws_size,
                              hipStream_t stream) {
  const float* ts = (const float*)d_in[0];
  const float* i1 = (const float*)d_in[1];
  const float* i2 = (const float*)d_in[2];
  float* out = (float*)d_out;

  char* p = (char*)d_ws;
  u16* reps    = (u16*)p;            p += (size_t)NREPS * ND * sizeof(u16);  // 12.6 MB
  float* norms = (float*)p;          p += (size_t)NREPS * sizeof(float);
  float* dist12 = (float*)p;         p += (size_t)NB * sizeof(float);
  u32* minsq   = (u32*)p;            p += (size_t)NB * sizeof(u32);
  float* lpos1 = (float*)p;          p += (size_t)NB * sizeof(float);
  float* lpos2 = (float*)p;          p += (size_t)NB * sizeof(float);

  prep_all<<<NB, 256, 0, stream>>>(ts, i1, i2, reps, norms, dist12, minsq);
  gemm_min<<<(NB/BM) * (NREPS/BN), 512, 0, stream>>>(reps, norms, minsq, lpos1, lpos2);
  finalize<<<1, 1024, 0, stream>>>(lpos1, lpos2, dist12, minsq, out);
}